// Round 1
// baseline (7273.210 us; speedup 1.0000x reference)
//
#include <hip/hip_runtime.h>
#include <hip/hip_bf16.h>
#include <math.h>

// ---------------------------------------------------------------------------
// Pathology_Balanced_Prompting_Module — fp32 baseline implementation.
// B=512, H=8, DK=64, D=512. ~380 GFLOP of GEMMs + small attention/LN kernels.
// Strategy R1: correct fp32 everywhere; tiled 128x128 GEMM (8x8/thread) with
// fused epilogues. MFMA conversion planned for later rounds.
// ---------------------------------------------------------------------------

#define BM 128
#define BN 128
#define BK 16

// EPI: 0 = bias, 1 = relu(bias), 2 = bias + residual, 4 = 0.9*res + 0.1*sigmoid(bias)
template<int EPI>
__global__ __launch_bounds__(256) void gemm_k(
    const float* __restrict__ A, int lda,
    const float* __restrict__ W,
    const float* __restrict__ bias,
    const float* __restrict__ res,
    float* __restrict__ C,
    int M, int N, int K)
{
    __shared__ float As[BK][BM + 8];   // row stride 136 floats = 544B (16B-divisible)
    __shared__ float Bs[BK][BN + 8];

    const int tid  = threadIdx.x;
    const int tx   = tid & 15;          // col group
    const int ty   = tid >> 4;          // row group
    const int row0 = blockIdx.y * BM;
    const int col0 = blockIdx.x * BN;

    const int la_r = tid >> 1;          // 0..127
    const int la_k = (tid & 1) * 8;     // 0 or 8
    const int lb_k = tid >> 4;          // 0..15
    const int lb_n = (tid & 15) * 8;    // 0..120

    float acc[8][8];
#pragma unroll
    for (int i = 0; i < 8; ++i)
#pragma unroll
        for (int j = 0; j < 8; ++j) acc[i][j] = 0.f;

    for (int k0 = 0; k0 < K; k0 += BK) {
        // ---- A tile: rows row0..row0+127, cols k0..k0+15 (M always %128==0 here)
        {
            const int ar = row0 + la_r;
            const float* pa = A + (size_t)ar * lda + k0 + la_k;
            float av[8];
            if (k0 + la_k + 7 < K) {
                float4 t0 = *(const float4*)(pa);
                float4 t1 = *(const float4*)(pa + 4);
                av[0]=t0.x; av[1]=t0.y; av[2]=t0.z; av[3]=t0.w;
                av[4]=t1.x; av[5]=t1.y; av[6]=t1.z; av[7]=t1.w;
            } else {
#pragma unroll
                for (int i = 0; i < 8; ++i)
                    av[i] = (k0 + la_k + i < K) ? pa[i] : 0.f;
            }
#pragma unroll
            for (int i = 0; i < 8; ++i) As[la_k + i][la_r] = av[i];
        }
        // ---- B tile: rows k0..k0+15, cols col0..col0+127
        {
            const int bk = k0 + lb_k;
            float4 b0, b1;
            if (bk < K && ((N & 3) == 0) && (col0 + lb_n + 7 < N)) {
                const float* pb = W + (size_t)bk * N + col0 + lb_n;
                b0 = *(const float4*)pb;
                b1 = *(const float4*)(pb + 4);
            } else {
                float tv[8];
#pragma unroll
                for (int i = 0; i < 8; ++i) {
                    int c = col0 + lb_n + i;
                    tv[i] = (bk < K && c < N) ? W[(size_t)bk * N + c] : 0.f;
                }
                b0 = make_float4(tv[0], tv[1], tv[2], tv[3]);
                b1 = make_float4(tv[4], tv[5], tv[6], tv[7]);
            }
            *(float4*)&Bs[lb_k][lb_n]     = b0;
            *(float4*)&Bs[lb_k][lb_n + 4] = b1;
        }
        __syncthreads();

#pragma unroll
        for (int kk = 0; kk < BK; ++kk) {
            float a[8], b[8];
            // split row/col fragments: {ty*4, 64+ty*4} x {tx*4, 64+tx*4}
            *(float4*)&a[0] = *(const float4*)&As[kk][ty * 4];
            *(float4*)&a[4] = *(const float4*)&As[kk][64 + ty * 4];
            *(float4*)&b[0] = *(const float4*)&Bs[kk][tx * 4];
            *(float4*)&b[4] = *(const float4*)&Bs[kk][64 + tx * 4];
#pragma unroll
            for (int i = 0; i < 8; ++i)
#pragma unroll
                for (int j = 0; j < 8; ++j)
                    acc[i][j] = fmaf(a[i], b[j], acc[i][j]);
        }
        __syncthreads();
    }

    // ---- epilogue: rows {row0+ig*64+ty*4+ii}, cols {col0+jg*64+tx*4+jj}
    const bool nvec = ((N & 3) == 0);
#pragma unroll
    for (int ig = 0; ig < 2; ++ig) {
#pragma unroll
        for (int ii = 0; ii < 4; ++ii) {
            const int r = row0 + ig * 64 + ty * 4 + ii;
            if (r >= M) continue;
            const size_t rb = (size_t)r * N;
            const int i = ig * 4 + ii;
#pragma unroll
            for (int jg = 0; jg < 2; ++jg) {
                const int c0 = col0 + jg * 64 + tx * 4;
                if (nvec && (c0 + 3 < N)) {
                    float v[4];
#pragma unroll
                    for (int jj = 0; jj < 4; ++jj) v[jj] = acc[i][jg * 4 + jj] + bias[c0 + jj];
                    if (EPI == 1) {
#pragma unroll
                        for (int jj = 0; jj < 4; ++jj) v[jj] = fmaxf(v[jj], 0.f);
                    }
                    if (EPI == 2) {
                        float4 rr = *(const float4*)&res[rb + c0];
                        v[0] += rr.x; v[1] += rr.y; v[2] += rr.z; v[3] += rr.w;
                    }
                    if (EPI == 4) {
                        float4 rr = *(const float4*)&res[rb + c0];
                        v[0] = 0.9f * rr.x + 0.1f * (1.f / (1.f + __expf(-v[0])));
                        v[1] = 0.9f * rr.y + 0.1f * (1.f / (1.f + __expf(-v[1])));
                        v[2] = 0.9f * rr.z + 0.1f * (1.f / (1.f + __expf(-v[2])));
                        v[3] = 0.9f * rr.w + 0.1f * (1.f / (1.f + __expf(-v[3])));
                    }
                    float4 o = make_float4(v[0], v[1], v[2], v[3]);
                    *(float4*)&C[rb + c0] = o;
                } else {
#pragma unroll
                    for (int jj = 0; jj < 4; ++jj) {
                        const int c = c0 + jj;
                        if (c >= N) continue;
                        float v = acc[i][jg * 4 + jj] + bias[c];
                        if (EPI == 1) v = fmaxf(v, 0.f);
                        if (EPI == 2) v += res[rb + c];
                        if (EPI == 4) v = 0.9f * res[rb + c] + 0.1f * (1.f / (1.f + __expf(-v)));
                        C[rb + c] = v;
                    }
                }
            }
        }
    }
}

// ---------------------------------------------------------------------------
// LayerNorm: one block (256 thr) per row of 512. Matches reference exactly:
// std = sqrt(sum((x-mean)^2)/511); out = g*(x-mean)/(std+1e-6) + b
// ---------------------------------------------------------------------------
__global__ __launch_bounds__(256) void ln_k(
    const float* __restrict__ x, const float* __restrict__ g,
    const float* __restrict__ b, float* __restrict__ out)
{
    const int row = blockIdx.x;
    const int tid = threadIdx.x;
    const float* xr = x + (size_t)row * 512;
    float v0 = xr[tid], v1 = xr[tid + 256];

    __shared__ float red[4];
    float s = v0 + v1;
#pragma unroll
    for (int off = 32; off >= 1; off >>= 1) s += __shfl_down(s, off);
    if ((tid & 63) == 0) red[tid >> 6] = s;
    __syncthreads();
    const float mean = (red[0] + red[1] + red[2] + red[3]) * (1.f / 512.f);
    const float d0 = v0 - mean, d1 = v1 - mean;
    __syncthreads();

    float ss = d0 * d0 + d1 * d1;
#pragma unroll
    for (int off = 32; off >= 1; off >>= 1) ss += __shfl_down(ss, off);
    if ((tid & 63) == 0) red[tid >> 6] = ss;
    __syncthreads();
    const float var = (red[0] + red[1] + red[2] + red[3]) * (1.f / 511.f);
    const float inv = 1.f / (sqrtf(var) + 1e-6f);

    float* orow = out + (size_t)row * 512;
    orow[tid]       = g[tid]       * (d0 * inv) + b[tid];
    orow[tid + 256] = g[tid + 256] * (d1 * inv) + b[tid + 256];
}

// ---------------------------------------------------------------------------
// Cross-attention: q has 33 tokens, k/v 24 tokens. One block per (h, b).
// Layouts are (b, t, h*64+d) — no physical transposes.
// ---------------------------------------------------------------------------
__global__ __launch_bounds__(256) void cross_attn_k(
    const float* __restrict__ q, const float* __restrict__ k,
    const float* __restrict__ v, float* __restrict__ out)
{
    const int h = blockIdx.x, b = blockIdx.y, tid = threadIdx.x;
    __shared__ float Lq[33 * 64], Lk[24 * 64], Lv[24 * 64], Ls[33 * 24];
    const size_t qoff = ((size_t)b * 33) * 512 + h * 64;
    const size_t koff = ((size_t)b * 24) * 512 + h * 64;

    for (int i = tid; i < 33 * 64; i += 256) {
        int t = i >> 6, d = i & 63;
        Lq[i] = q[qoff + (size_t)t * 512 + d];
    }
    for (int i = tid; i < 24 * 64; i += 256) {
        int t = i >> 6, d = i & 63;
        Lk[i] = k[koff + (size_t)t * 512 + d];
        Lv[i] = v[koff + (size_t)t * 512 + d];
    }
    __syncthreads();

    for (int i = tid; i < 33 * 24; i += 256) {
        int r = i / 24, c = i % 24;
        float s = 0.f;
#pragma unroll
        for (int d = 0; d < 64; ++d) s = fmaf(Lq[r * 64 + d], Lk[c * 64 + d], s);
        Ls[i] = s * 0.125f;
    }
    __syncthreads();

    if (tid < 33) {
        float mx = -1e30f;
        for (int c = 0; c < 24; ++c) mx = fmaxf(mx, Ls[tid * 24 + c]);
        float sum = 0.f;
        for (int c = 0; c < 24; ++c) { float e = __expf(Ls[tid * 24 + c] - mx); Ls[tid * 24 + c] = e; sum += e; }
        float inv = 1.f / sum;
        for (int c = 0; c < 24; ++c) Ls[tid * 24 + c] *= inv;
    }
    __syncthreads();

    for (int i = tid; i < 33 * 64; i += 256) {
        int r = i >> 6, d = i & 63;
        float a = 0.f;
#pragma unroll
        for (int c = 0; c < 24; ++c) a = fmaf(Ls[r * 24 + c], Lv[c * 64 + d], a);
        out[qoff + (size_t)r * 512 + d] = a;
    }
}

// ---------------------------------------------------------------------------
// Masked self-attention (33 tokens), mask adj (b,33,33), know=True:
// s = (q.kT/8) * m; s = (m==0) ? -1e9 : s; softmax; out = p @ v
// ---------------------------------------------------------------------------
__global__ __launch_bounds__(256) void self_attn_k(
    const float* __restrict__ q, const float* __restrict__ k,
    const float* __restrict__ v, const float* __restrict__ adj,
    float* __restrict__ out)
{
    const int h = blockIdx.x, b = blockIdx.y, tid = threadIdx.x;
    __shared__ float Lq[33 * 64], Lk[33 * 64], Lv[33 * 64], Ls[33 * 34], Lm[33 * 33];
    const size_t off = ((size_t)b * 33) * 512 + h * 64;

    for (int i = tid; i < 33 * 64; i += 256) {
        int t = i >> 6, d = i & 63;
        Lq[i] = q[off + (size_t)t * 512 + d];
        Lk[i] = k[off + (size_t)t * 512 + d];
        Lv[i] = v[off + (size_t)t * 512 + d];
    }
    for (int i = tid; i < 1089; i += 256) Lm[i] = adj[(size_t)b * 1089 + i];
    __syncthreads();

    for (int i = tid; i < 1089; i += 256) {
        int r = i / 33, c = i % 33;
        float s = 0.f;
#pragma unroll
        for (int d = 0; d < 64; ++d) s = fmaf(Lq[r * 64 + d], Lk[c * 64 + d], s);
        s *= 0.125f;
        float m = Lm[i];
        s = (m == 0.f) ? -1e9f : s * m;
        Ls[r * 34 + c] = s;
    }
    __syncthreads();

    if (tid < 33) {
        float mx = -1e30f;
        for (int c = 0; c < 33; ++c) mx = fmaxf(mx, Ls[tid * 34 + c]);
        float sum = 0.f;
        for (int c = 0; c < 33; ++c) { float e = __expf(Ls[tid * 34 + c] - mx); Ls[tid * 34 + c] = e; sum += e; }
        float inv = 1.f / sum;
        for (int c = 0; c < 33; ++c) Ls[tid * 34 + c] *= inv;
    }
    __syncthreads();

    for (int i = tid; i < 33 * 64; i += 256) {
        int r = i >> 6, d = i & 63;
        float a = 0.f;
#pragma unroll
        for (int c = 0; c < 33; ++c) a = fmaf(Ls[r * 34 + c], Lv[c * 64 + d], a);
        out[off + (size_t)r * 512 + d] = a;
    }
}

// ---------------------------------------------------------------------------
// rel[b,i,j] = er[b,i,:] . er[b,j,:]  (512-dot). Output row-padded to 1104
// so the downstream pred-GEMM A-loads stay 16B aligned. Two K-halves so the
// LDS stage fits the 64KB static-shared cap (33*256*4 = 33.8KB).
// ---------------------------------------------------------------------------
__global__ __launch_bounds__(256) void rel_k(
    const float* __restrict__ er, float* __restrict__ rel)
{
    const int b = blockIdx.x, tid = threadIdx.x;
    __shared__ float E[33 * 256];
    const float* src = er + (size_t)b * 33 * 512;

    float accv[5] = {0.f, 0.f, 0.f, 0.f, 0.f};
    for (int half = 0; half < 2; ++half) {
        for (int i = tid; i < 33 * 256; i += 256) {
            int t = i >> 8, d = i & 255;
            E[i] = src[(size_t)t * 512 + half * 256 + d];
        }
        __syncthreads();
        for (int u = 0; u < 5; ++u) {
            int i = tid + 256 * u;
            if (i < 1089) {
                int r = i / 33, c = i % 33;
                const float* pr = &E[r * 256];
                const float* pc = &E[c * 256];
                float a = accv[u];
                for (int d = 0; d < 256; d += 4) {
                    float4 x = *(const float4*)&pr[d];
                    float4 y = *(const float4*)&pc[d];
                    a = fmaf(x.x, y.x, fmaf(x.y, y.y, fmaf(x.z, y.z, fmaf(x.w, y.w, a))));
                }
                accv[u] = a;
            }
        }
        __syncthreads();
    }
    for (int u = 0; u < 5; ++u) {
        int i = tid + 256 * u;
        if (i < 1089) rel[(size_t)b * 1104 + i] = accv[u];
    }
}

// ---------------------------------------------------------------------------
// Classifier head: per-batch-row GEMV, M=512 rows, K=4224, N=32, + sigmoid.
// One block per row; 8 K-groups x 32 output lanes.
// ---------------------------------------------------------------------------
__global__ __launch_bounds__(256) void cls_k(
    const float* __restrict__ cin, const float* __restrict__ W,
    const float* __restrict__ bias, float* __restrict__ out)
{
    const int b = blockIdx.x, tid = threadIdx.x;
    const int n = tid & 31, kg = tid >> 5;
    const float* x = cin + (size_t)b * 4224;
    float acc = 0.f;
    for (int k = kg; k < 4224; k += 8)
        acc = fmaf(x[k], W[(size_t)k * 32 + n], acc);

    __shared__ float part[8][32];
    part[kg][n] = acc;
    __syncthreads();
    if (tid < 32) {
        float s = bias[tid];
#pragma unroll
        for (int g = 0; g < 8; ++g) s += part[g][tid];
        out[(size_t)b * 32 + tid] = 1.f / (1.f + __expf(-s));
    }
}

// ---------------------------------------------------------------------------
// Host orchestration
// ---------------------------------------------------------------------------
static inline void launch_gemm(int epi, const float* A, int lda, const float* W,
                               const float* bias, const float* res, float* C,
                               int M, int N, int K, hipStream_t stream)
{
    dim3 g((N + BN - 1) / BN, (M + BM - 1) / BM), blk(256);
    switch (epi) {
    case 0: gemm_k<0><<<g, blk, 0, stream>>>(A, lda, W, bias, res, C, M, N, K); break;
    case 1: gemm_k<1><<<g, blk, 0, stream>>>(A, lda, W, bias, res, C, M, N, K); break;
    case 2: gemm_k<2><<<g, blk, 0, stream>>>(A, lda, W, bias, res, C, M, N, K); break;
    case 4: gemm_k<4><<<g, blk, 0, stream>>>(A, lda, W, bias, res, C, M, N, K); break;
    }
}

extern "C" void kernel_launch(void* const* d_in, const int* in_sizes, int n_in,
                              void* d_out, int out_size, void* d_ws, size_t ws_size,
                              hipStream_t stream)
{
    const float* visual   = (const float*)d_in[0];
    const float* entity   = (const float*)d_in[1];
    const float* graph    = (const float*)d_in[2];
    const float* vis_W    = (const float*)d_in[3];
    const float* vis_b    = (const float*)d_in[4];
    const float* ent_W    = (const float*)d_in[5];
    const float* ent_b    = (const float*)d_in[6];
    const float* ca_Wq    = (const float*)d_in[7];
    const float* ca_bq    = (const float*)d_in[8];
    const float* ca_Wk    = (const float*)d_in[9];
    const float* ca_bk    = (const float*)d_in[10];
    const float* ca_Wv    = (const float*)d_in[11];
    const float* ca_bv    = (const float*)d_in[12];
    const float* ca_Wo    = (const float*)d_in[13];
    const float* ca_bo    = (const float*)d_in[14];
    const float* kp_W     = (const float*)d_in[15];
    const float* kp_b     = (const float*)d_in[16];
    const float* pred_W   = (const float*)d_in[17];
    const float* pred_b   = (const float*)d_in[18];
    const float* l_Wq     = (const float*)d_in[19];
    const float* l_bq     = (const float*)d_in[20];
    const float* l_Wk     = (const float*)d_in[21];
    const float* l_bk     = (const float*)d_in[22];
    const float* l_Wv     = (const float*)d_in[23];
    const float* l_bv     = (const float*)d_in[24];
    const float* l_Wo     = (const float*)d_in[25];
    const float* l_bo     = (const float*)d_in[26];
    const float* l_ffW1   = (const float*)d_in[27];
    const float* l_ffb1   = (const float*)d_in[28];
    const float* l_ffW2   = (const float*)d_in[29];
    const float* l_ffb2   = (const float*)d_in[30];
    const float* l_n1_g   = (const float*)d_in[31];
    const float* l_n1_b   = (const float*)d_in[32];
    const float* l_n2_g   = (const float*)d_in[33];
    const float* l_n2_b   = (const float*)d_in[34];
    const float* fin_g    = (const float*)d_in[35];
    const float* fin_b    = (const float*)d_in[36];
    const float* ad_W1    = (const float*)d_in[37];
    const float* ad_b1    = (const float*)d_in[38];
    const float* ad_W2    = (const float*)d_in[39];
    const float* ad_b2    = (const float*)d_in[40];
    const float* sc_fc_W  = (const float*)d_in[41];
    const float* sc_fc_b  = (const float*)d_in[42];
    const float* sc_cls_W = (const float*)d_in[43];
    const float* sc_cls_b = (const float*)d_in[44];

    const int B = 512;
    const int Mv = B * 24;   // 12288
    const int Me = B * 33;   // 16896

    // workspace layout (floats); total 52,830,720 floats = 211.3 MB
    float* ws    = (float*)d_ws;
    float* o_v   = ws;                          // 12288*512
    float* o_x   = o_v  + (size_t)Mv * 512;     // 16896*512
    float* o_xn  = o_x  + (size_t)Me * 512;
    float* o_q   = o_xn + (size_t)Me * 512;
    float* o_k   = o_q  + (size_t)Me * 512;
    float* o_vv  = o_k  + (size_t)Me * 512;
    float* o_rel = o_vv + (size_t)Me * 512;     // 512*1104 (padded)
    float* o_adj = o_rel + (size_t)B * 1104;    // 512*1089
    float* o_cls = o_adj + (size_t)B * 1089;    // 16896*128

    float* out_adapted = (float*)d_out;                       // 512*33*4096
    float* out_cls     = out_adapted + (size_t)Me * 4096;     // 512*32

    dim3 attn_grid(8, B), blk256(256);

    // ---- input projections
    launch_gemm(0, visual, 2048, vis_W, vis_b, nullptr, o_v,  Mv, 512, 2048, stream);
    launch_gemm(0, entity, 4096, ent_W, ent_b, nullptr, o_xn, Me, 512, 4096, stream);  // e -> o_xn

    // ---- cross attention (q from e, k/v from v)
    launch_gemm(0, o_xn, 512, ca_Wq, ca_bq, nullptr, o_q,  Me, 512, 512, stream);
    launch_gemm(0, o_v,  512, ca_Wk, ca_bk, nullptr, o_k,  Mv, 512, 512, stream);
    launch_gemm(0, o_v,  512, ca_Wv, ca_bv, nullptr, o_vv, Mv, 512, 512, stream);
    cross_attn_k<<<attn_grid, blk256, 0, stream>>>(o_q, o_k, o_vv, o_xn);   // attc -> o_xn (e dead)
    launch_gemm(0, o_xn, 512, ca_Wo, ca_bo, nullptr, o_x, Me, 512, 512, stream);       // ef -> o_x

    // ---- knowledge path: er, rel, emp, adj
    launch_gemm(0, o_x, 512, kp_W, kp_b, nullptr, o_q, Me, 512, 512, stream);          // er -> o_q
    rel_k<<<B, blk256, 0, stream>>>(o_q, o_rel);
    launch_gemm(4, o_rel, 1104, pred_W, pred_b, graph, o_adj, B, 1089, 1089, stream);  // adj

    // ---- 3 transformer layers
    for (int i = 0; i < 3; ++i) {
        const float* Wq = l_Wq + (size_t)i * 512 * 512;
        const float* bq = l_bq + (size_t)i * 512;
        const float* Wk = l_Wk + (size_t)i * 512 * 512;
        const float* bk = l_bk + (size_t)i * 512;
        const float* Wv = l_Wv + (size_t)i * 512 * 512;
        const float* bv = l_bv + (size_t)i * 512;
        const float* Wo = l_Wo + (size_t)i * 512 * 512;
        const float* bo = l_bo + (size_t)i * 512;
        const float* W1 = l_ffW1 + (size_t)i * 512 * 512;
        const float* b1 = l_ffb1 + (size_t)i * 512;
        const float* W2 = l_ffW2 + (size_t)i * 512 * 512;
        const float* b2 = l_ffb2 + (size_t)i * 512;

        ln_k<<<Me, blk256, 0, stream>>>(o_x, l_n1_g + (size_t)i * 512, l_n1_b + (size_t)i * 512, o_xn);
        launch_gemm(0, o_xn, 512, Wq, bq, nullptr, o_q,  Me, 512, 512, stream);
        launch_gemm(0, o_x,  512, Wk, bk, nullptr, o_k,  Me, 512, 512, stream);
        launch_gemm(0, o_x,  512, Wv, bv, nullptr, o_vv, Me, 512, 512, stream);
        self_attn_k<<<attn_grid, blk256, 0, stream>>>(o_q, o_k, o_vv, o_adj, o_xn);    // attc -> o_xn
        launch_gemm(2, o_xn, 512, Wo, bo, o_x, o_x, Me, 512, 512, stream);             // x += attc@Wo
        ln_k<<<Me, blk256, 0, stream>>>(o_x, l_n2_g + (size_t)i * 512, l_n2_b + (size_t)i * 512, o_xn);
        launch_gemm(1, o_xn, 512, W1, b1, nullptr, o_q, Me, 512, 512, stream);         // relu
        launch_gemm(2, o_q,  512, W2, b2, o_x, o_x, Me, 512, 512, stream);             // x += ff
    }

    // ---- final LN + heads
    ln_k<<<Me, blk256, 0, stream>>>(o_x, fin_g, fin_b, o_xn);                          // emb -> o_xn
    launch_gemm(0, o_xn, 512, ad_W1, ad_b1, nullptr, o_q, Me, 512, 512, stream);
    launch_gemm(0, o_q,  512, ad_W2, ad_b2, nullptr, out_adapted, Me, 4096, 512, stream);
    launch_gemm(0, o_xn, 512, sc_fc_W, sc_fc_b, nullptr, o_cls, Me, 128, 512, stream);
    cls_k<<<B, blk256, 0, stream>>>(o_cls, sc_cls_W, sc_cls_b, out_cls);
}

// Round 2
// 3405.096 us; speedup vs baseline: 2.1360x; 2.1360x over previous
//
#include <hip/hip_runtime.h>
#include <hip/hip_bf16.h>
#include <math.h>

// ---------------------------------------------------------------------------
// R2: all GEMMs -> bf16 MFMA (16x16x32), fp32 accumulate.
// Dataflow: activations maintained in bf16; fp32 kept only for the residual
// stream (o_x), adj, and final outputs. Weights transposed+converted to
// bf16 [N][K] once per call by a batched kernel.
// ---------------------------------------------------------------------------

typedef unsigned short ushort_t;
typedef short short8 __attribute__((ext_vector_type(8)));
typedef float floatx4 __attribute__((ext_vector_type(4)));

__device__ __forceinline__ unsigned short f2u(float f) {
    union { float f; unsigned u; } x; x.f = f;
    unsigned r = x.u + 0x7fffu + ((x.u >> 16) & 1u);   // round-to-nearest-even
    return (unsigned short)(r >> 16);
}
__device__ __forceinline__ float u2f(unsigned short u) {
    union { unsigned u; float f; } x; x.u = ((unsigned)u) << 16; return x.f;
}

// ---------------------------------------------------------------------------
// Batched weight transpose+convert: src fp32 [K][N] -> dst bf16 [N][Kd]
// (Kd >= K, zero-padded). One launch for all 29 weights.
// ---------------------------------------------------------------------------
struct WJob { const float* src; ushort_t* dst; int K; int N; int Kd; int block0; };
struct WJobs { WJob j[29]; int n; };

__global__ __launch_bounds__(256) void wcvt_k(WJobs jb)
{
    const int bid = blockIdx.x, tid = threadIdx.x;
    int ji = 0;
    for (int t = 1; t < jb.n; ++t) if (jb.j[t].block0 <= bid) ji = t;
    const WJob w = jb.j[ji];
    const int lb = bid - w.block0;
    const int tilesN = (w.N + 31) >> 5;
    const int tk = lb / tilesN, tn = lb - tk * tilesN;
    const int k0 = tk * 32, n0 = tn * 32;
    __shared__ float T[32][33];
    const int c = tid & 31, rr = tid >> 5;
#pragma unroll
    for (int p = 0; p < 4; ++p) {
        int r = rr + p * 8;
        int k = k0 + r, n = n0 + c;
        T[r][c] = (k < w.K && n < w.N) ? w.src[(size_t)k * w.N + n] : 0.f;
    }
    __syncthreads();
#pragma unroll
    for (int p = 0; p < 4; ++p) {
        int r = rr + p * 8;
        int n = n0 + r, k = k0 + c;
        if (n < w.N && k < w.Kd) w.dst[(size_t)n * w.Kd + k] = f2u(T[c][r]);
    }
}

// ---------------------------------------------------------------------------
// MFMA GEMM: C[M,N] = A[M,K] @ B[K,N] (+bias, epilogues), B given as
// Bt[N][K] bf16. A is bf16 (AF32=false) or fp32 converted in staging.
// 128x128 tile, BK=64, 4 waves, each wave 64x64 via 4x4 of 16x16x32 MFMA.
// Fragment layout (m89-verified): A[m=lane&15][k=quad*8+j]; C col=lane&15,
// row=quad*4+reg. Requires M%128==0, K%64==0 (guaranteed by padding).
// EPI: 0=bias, 1=relu, 2=+res, 4=0.9*res+0.1*sigmoid
// ---------------------------------------------------------------------------
template<int EPI, bool AF32, bool WB, bool WF>
__global__ __launch_bounds__(256) void mfma_gemm(
    const void* __restrict__ Av, int lda,
    const ushort_t* __restrict__ Bt, int ldb,
    const float* __restrict__ bias,
    const float* __restrict__ res,
    float* __restrict__ Cf, ushort_t* __restrict__ Cb,
    int M, int N, int K)
{
    __shared__ __align__(16) ushort_t As[128][72];   // stride 144B: uniform banks
    __shared__ __align__(16) ushort_t Bs[128][72];

    const int tid  = threadIdx.x;
    const int lane = tid & 63, wave = tid >> 6;
    const int wr = (wave >> 1) * 64, wc = (wave & 1) * 64;
    const int lrow = lane & 15, quad = lane >> 4;
    const int row0 = blockIdx.y * 128, col0 = blockIdx.x * 128;

    const int srow  = tid >> 3;         // 0..31
    const int skoff = (tid & 7) * 8;    // 0..56 (bf16 elements)

    floatx4 acc[4][4];
#pragma unroll
    for (int i = 0; i < 4; ++i)
#pragma unroll
        for (int j = 0; j < 4; ++j) acc[i][j] = (floatx4){0.f, 0.f, 0.f, 0.f};

    for (int k0 = 0; k0 < K; k0 += 64) {
        // ---- stage A (128 x 64 bf16)
#pragma unroll
        for (int p = 0; p < 4; ++p) {
            const int r = p * 32 + srow;
            uint4 val;
            if (AF32) {
                const float* pa = (const float*)Av + (size_t)(row0 + r) * lda + k0 + skoff;
                float4 f0 = *(const float4*)pa;
                float4 f1 = *(const float4*)(pa + 4);
                val.x = (unsigned)f2u(f0.x) | ((unsigned)f2u(f0.y) << 16);
                val.y = (unsigned)f2u(f0.z) | ((unsigned)f2u(f0.w) << 16);
                val.z = (unsigned)f2u(f1.x) | ((unsigned)f2u(f1.y) << 16);
                val.w = (unsigned)f2u(f1.z) | ((unsigned)f2u(f1.w) << 16);
            } else {
                val = *(const uint4*)((const ushort_t*)Av + (size_t)(row0 + r) * lda + k0 + skoff);
            }
            *(uint4*)&As[r][skoff] = val;
        }
        // ---- stage B (128 cols x 64 bf16 from Bt[N][K]); zero OOB cols (pred)
#pragma unroll
        for (int p = 0; p < 4; ++p) {
            const int r = p * 32 + srow;
            const int n = col0 + r;
            uint4 val = make_uint4(0u, 0u, 0u, 0u);
            if (n < N) val = *(const uint4*)(Bt + (size_t)n * ldb + k0 + skoff);
            *(uint4*)&Bs[r][skoff] = val;
        }
        __syncthreads();

#pragma unroll
        for (int kk = 0; kk < 2; ++kk) {
            short8 af[4], bfr[4];
#pragma unroll
            for (int i = 0; i < 4; ++i)
                af[i] = *(const short8*)&As[wr + i * 16 + lrow][kk * 32 + quad * 8];
#pragma unroll
            for (int j = 0; j < 4; ++j)
                bfr[j] = *(const short8*)&Bs[wc + j * 16 + lrow][kk * 32 + quad * 8];
#pragma unroll
            for (int i = 0; i < 4; ++i)
#pragma unroll
                for (int j = 0; j < 4; ++j)
                    acc[i][j] = __builtin_amdgcn_mfma_f32_16x16x32_bf16(af[i], bfr[j], acc[i][j], 0, 0, 0);
        }
        __syncthreads();
    }

    // ---- epilogue
#pragma unroll
    for (int j = 0; j < 4; ++j) {
        const int col = col0 + wc + j * 16 + lrow;
        if (col >= N) continue;
        const float bv = bias[col];
#pragma unroll
        for (int i = 0; i < 4; ++i) {
#pragma unroll
            for (int r = 0; r < 4; ++r) {
                const int row = row0 + wr + i * 16 + quad * 4 + r;
                const size_t off = (size_t)row * N + col;
                float v = acc[i][j][r] + bv;
                if (EPI == 1) v = fmaxf(v, 0.f);
                if (EPI == 2) v += res[off];
                if (EPI == 4) v = 0.9f * res[off] + 0.1f * (1.f / (1.f + __expf(-v)));
                if (WF) Cf[off] = v;
                if (WB) Cb[off] = f2u(v);
            }
        }
    }
}

// ---------------------------------------------------------------------------
// LayerNorm: fp32 in, bf16 out. std = sqrt(sumsq/511); eps added to std.
// ---------------------------------------------------------------------------
__global__ __launch_bounds__(256) void ln_k(
    const float* __restrict__ x, const float* __restrict__ g,
    const float* __restrict__ b, ushort_t* __restrict__ out)
{
    const int row = blockIdx.x;
    const int tid = threadIdx.x;
    const float* xr = x + (size_t)row * 512;
    float v0 = xr[tid], v1 = xr[tid + 256];

    __shared__ float red[4];
    float s = v0 + v1;
#pragma unroll
    for (int off = 32; off >= 1; off >>= 1) s += __shfl_down(s, off);
    if ((tid & 63) == 0) red[tid >> 6] = s;
    __syncthreads();
    const float mean = (red[0] + red[1] + red[2] + red[3]) * (1.f / 512.f);
    const float d0 = v0 - mean, d1 = v1 - mean;
    __syncthreads();

    float ss = d0 * d0 + d1 * d1;
#pragma unroll
    for (int off = 32; off >= 1; off >>= 1) ss += __shfl_down(ss, off);
    if ((tid & 63) == 0) red[tid >> 6] = ss;
    __syncthreads();
    const float var = (red[0] + red[1] + red[2] + red[3]) * (1.f / 511.f);
    const float inv = 1.f / (sqrtf(var) + 1e-6f);

    ushort_t* orow = out + (size_t)row * 512;
    orow[tid]       = f2u(g[tid]       * (d0 * inv) + b[tid]);
    orow[tid + 256] = f2u(g[tid + 256] * (d1 * inv) + b[tid + 256]);
}

// ---------------------------------------------------------------------------
// Cross-attention (q:33 tok, k/v:24 tok). bf16 in/out, fp32 compute.
// ---------------------------------------------------------------------------
__global__ __launch_bounds__(256) void cross_attn_k(
    const ushort_t* __restrict__ q, const ushort_t* __restrict__ k,
    const ushort_t* __restrict__ v, ushort_t* __restrict__ out)
{
    const int h = blockIdx.x, b = blockIdx.y, tid = threadIdx.x;
    __shared__ float Lq[33 * 64], Lk[24 * 64], Lv[24 * 64], Ls[33 * 24];
    const size_t qoff = ((size_t)b * 33) * 512 + h * 64;
    const size_t koff = ((size_t)b * 24) * 512 + h * 64;

    for (int i = tid; i < 33 * 64; i += 256) {
        int t = i >> 6, d = i & 63;
        Lq[i] = u2f(q[qoff + (size_t)t * 512 + d]);
    }
    for (int i = tid; i < 24 * 64; i += 256) {
        int t = i >> 6, d = i & 63;
        Lk[i] = u2f(k[koff + (size_t)t * 512 + d]);
        Lv[i] = u2f(v[koff + (size_t)t * 512 + d]);
    }
    __syncthreads();

    for (int i = tid; i < 33 * 24; i += 256) {
        int r = i / 24, c = i % 24;
        float s = 0.f;
#pragma unroll
        for (int d = 0; d < 64; ++d) s = fmaf(Lq[r * 64 + d], Lk[c * 64 + d], s);
        Ls[i] = s * 0.125f;
    }
    __syncthreads();

    if (tid < 33) {
        float mx = -1e30f;
        for (int c = 0; c < 24; ++c) mx = fmaxf(mx, Ls[tid * 24 + c]);
        float sum = 0.f;
        for (int c = 0; c < 24; ++c) { float e = __expf(Ls[tid * 24 + c] - mx); Ls[tid * 24 + c] = e; sum += e; }
        float inv = 1.f / sum;
        for (int c = 0; c < 24; ++c) Ls[tid * 24 + c] *= inv;
    }
    __syncthreads();

    for (int i = tid; i < 33 * 64; i += 256) {
        int r = i >> 6, d = i & 63;
        float a = 0.f;
#pragma unroll
        for (int c = 0; c < 24; ++c) a = fmaf(Ls[r * 24 + c], Lv[c * 64 + d], a);
        out[qoff + (size_t)r * 512 + d] = f2u(a);
    }
}

// ---------------------------------------------------------------------------
// Masked self-attention (33 tok), adj fp32, know=True semantics.
// ---------------------------------------------------------------------------
__global__ __launch_bounds__(256) void self_attn_k(
    const ushort_t* __restrict__ q, const ushort_t* __restrict__ k,
    const ushort_t* __restrict__ v, const float* __restrict__ adj,
    ushort_t* __restrict__ out)
{
    const int h = blockIdx.x, b = blockIdx.y, tid = threadIdx.x;
    __shared__ float Lq[33 * 64], Lk[33 * 64], Lv[33 * 64], Ls[33 * 34], Lm[33 * 33];
    const size_t off = ((size_t)b * 33) * 512 + h * 64;

    for (int i = tid; i < 33 * 64; i += 256) {
        int t = i >> 6, d = i & 63;
        Lq[i] = u2f(q[off + (size_t)t * 512 + d]);
        Lk[i] = u2f(k[off + (size_t)t * 512 + d]);
        Lv[i] = u2f(v[off + (size_t)t * 512 + d]);
    }
    for (int i = tid; i < 1089; i += 256) Lm[i] = adj[(size_t)b * 1089 + i];
    __syncthreads();

    for (int i = tid; i < 1089; i += 256) {
        int r = i / 33, c = i % 33;
        float s = 0.f;
#pragma unroll
        for (int d = 0; d < 64; ++d) s = fmaf(Lq[r * 64 + d], Lk[c * 64 + d], s);
        s *= 0.125f;
        float m = Lm[i];
        s = (m == 0.f) ? -1e9f : s * m;
        Ls[r * 34 + c] = s;
    }
    __syncthreads();

    if (tid < 33) {
        float mx = -1e30f;
        for (int c = 0; c < 33; ++c) mx = fmaxf(mx, Ls[tid * 34 + c]);
        float sum = 0.f;
        for (int c = 0; c < 33; ++c) { float e = __expf(Ls[tid * 34 + c] - mx); Ls[tid * 34 + c] = e; sum += e; }
        float inv = 1.f / sum;
        for (int c = 0; c < 33; ++c) Ls[tid * 34 + c] *= inv;
    }
    __syncthreads();

    for (int i = tid; i < 33 * 64; i += 256) {
        int r = i >> 6, d = i & 63;
        float a = 0.f;
#pragma unroll
        for (int c = 0; c < 33; ++c) a = fmaf(Ls[r * 34 + c], Lv[c * 64 + d], a);
        out[off + (size_t)r * 512 + d] = f2u(a);
    }
}

// ---------------------------------------------------------------------------
// rel[b,i,j] = er[b,i,:].er[b,j,:]. bf16 in, bf16 out padded to K=1152
// (zeros at 1089..1151) for the pred GEMM.
// ---------------------------------------------------------------------------
__global__ __launch_bounds__(256) void rel_k(
    const ushort_t* __restrict__ er, ushort_t* __restrict__ rel)
{
    const int b = blockIdx.x, tid = threadIdx.x;
    __shared__ float E[33 * 256];
    const ushort_t* src = er + (size_t)b * 33 * 512;

    float accv[5] = {0.f, 0.f, 0.f, 0.f, 0.f};
    for (int half = 0; half < 2; ++half) {
        for (int i = tid; i < 33 * 256; i += 256) {
            int t = i >> 8, d = i & 255;
            E[i] = u2f(src[(size_t)t * 512 + half * 256 + d]);
        }
        __syncthreads();
        for (int u = 0; u < 5; ++u) {
            int i = tid + 256 * u;
            if (i < 1089) {
                int r = i / 33, c = i % 33;
                const float* pr = &E[r * 256];
                const float* pc = &E[c * 256];
                float a = accv[u];
                for (int d = 0; d < 256; d += 4) {
                    float4 x = *(const float4*)&pr[d];
                    float4 y = *(const float4*)&pc[d];
                    a = fmaf(x.x, y.x, fmaf(x.y, y.y, fmaf(x.z, y.z, fmaf(x.w, y.w, a))));
                }
                accv[u] = a;
            }
        }
        __syncthreads();
    }
    for (int u = 0; u < 5; ++u) {
        int i = tid + 256 * u;
        if (i < 1089) rel[(size_t)b * 1152 + i] = f2u(accv[u]);
    }
    for (int i = 1089 + tid; i < 1152; i += 256) rel[(size_t)b * 1152 + i] = 0;
}

// ---------------------------------------------------------------------------
// Classifier head: bf16 cin (512 x 4224), fp32 W (4224 x 32) + sigmoid.
// ---------------------------------------------------------------------------
__global__ __launch_bounds__(256) void cls_k(
    const ushort_t* __restrict__ cin, const float* __restrict__ W,
    const float* __restrict__ bias, float* __restrict__ out)
{
    const int b = blockIdx.x, tid = threadIdx.x;
    const int n = tid & 31, kg = tid >> 5;
    const ushort_t* x = cin + (size_t)b * 4224;
    float acc = 0.f;
    for (int k = kg; k < 4224; k += 8)
        acc = fmaf(u2f(x[k]), W[(size_t)k * 32 + n], acc);

    __shared__ float part[8][32];
    part[kg][n] = acc;
    __syncthreads();
    if (tid < 32) {
        float s = bias[tid];
#pragma unroll
        for (int g = 0; g < 8; ++g) s += part[g][tid];
        out[(size_t)b * 32 + tid] = 1.f / (1.f + __expf(-s));
    }
}

// ---------------------------------------------------------------------------
// Host orchestration
// ---------------------------------------------------------------------------
extern "C" void kernel_launch(void* const* d_in, const int* in_sizes, int n_in,
                              void* d_out, int out_size, void* d_ws, size_t ws_size,
                              hipStream_t stream)
{
    const float* visual   = (const float*)d_in[0];
    const float* entity   = (const float*)d_in[1];
    const float* graph    = (const float*)d_in[2];
    const float* vis_W    = (const float*)d_in[3];
    const float* vis_b    = (const float*)d_in[4];
    const float* ent_W    = (const float*)d_in[5];
    const float* ent_b    = (const float*)d_in[6];
    const float* ca_Wq    = (const float*)d_in[7];
    const float* ca_bq    = (const float*)d_in[8];
    const float* ca_Wk    = (const float*)d_in[9];
    const float* ca_bk    = (const float*)d_in[10];
    const float* ca_Wv    = (const float*)d_in[11];
    const float* ca_bv    = (const float*)d_in[12];
    const float* ca_Wo    = (const float*)d_in[13];
    const float* ca_bo    = (const float*)d_in[14];
    const float* kp_W     = (const float*)d_in[15];
    const float* kp_b     = (const float*)d_in[16];
    const float* pred_W   = (const float*)d_in[17];
    const float* pred_b   = (const float*)d_in[18];
    const float* l_Wq     = (const float*)d_in[19];
    const float* l_bq     = (const float*)d_in[20];
    const float* l_Wk     = (const float*)d_in[21];
    const float* l_bk     = (const float*)d_in[22];
    const float* l_Wv     = (const float*)d_in[23];
    const float* l_bv     = (const float*)d_in[24];
    const float* l_Wo     = (const float*)d_in[25];
    const float* l_bo     = (const float*)d_in[26];
    const float* l_ffW1   = (const float*)d_in[27];
    const float* l_ffb1   = (const float*)d_in[28];
    const float* l_ffW2   = (const float*)d_in[29];
    const float* l_ffb2   = (const float*)d_in[30];
    const float* l_n1_g   = (const float*)d_in[31];
    const float* l_n1_b   = (const float*)d_in[32];
    const float* l_n2_g   = (const float*)d_in[33];
    const float* l_n2_b   = (const float*)d_in[34];
    const float* fin_g    = (const float*)d_in[35];
    const float* fin_b    = (const float*)d_in[36];
    const float* ad_W1    = (const float*)d_in[37];
    const float* ad_b1    = (const float*)d_in[38];
    const float* ad_W2    = (const float*)d_in[39];
    const float* ad_b2    = (const float*)d_in[40];
    const float* sc_fc_W  = (const float*)d_in[41];
    const float* sc_fc_b  = (const float*)d_in[42];
    const float* sc_cls_W = (const float*)d_in[43];
    const float* sc_cls_b = (const float*)d_in[44];

    const int B  = 512;
    const int Mv = B * 24;   // 12288
    const int Me = B * 33;   // 16896

    // ---- workspace layout
    char* wsb = (char*)d_ws;
    size_t off = 0;
    auto alloc_us = [&](size_t elems) -> ushort_t* {
        ushort_t* p = (ushort_t*)(wsb + off); off += ((elems * 2 + 255) & ~(size_t)255); return p; };
    auto alloc_f = [&](size_t elems) -> float* {
        float* p = (float*)(wsb + off); off += ((elems * 4 + 255) & ~(size_t)255); return p; };

    // weight (bf16, transposed) region
    ushort_t* vis_Wt = alloc_us((size_t)512 * 2048);
    ushort_t* ent_Wt = alloc_us((size_t)512 * 4096);
    ushort_t* caq_t  = alloc_us((size_t)512 * 512);
    ushort_t* cak_t  = alloc_us((size_t)512 * 512);
    ushort_t* cav_t  = alloc_us((size_t)512 * 512);
    ushort_t* cao_t  = alloc_us((size_t)512 * 512);
    ushort_t* kp_t   = alloc_us((size_t)512 * 512);
    ushort_t* pred_t = alloc_us((size_t)1089 * 1152);
    ushort_t* lw_t   = alloc_us((size_t)18 * 512 * 512);   // [layer*6 + slot]
    ushort_t* ad1_t  = alloc_us((size_t)512 * 512);
    ushort_t* ad2_t  = alloc_us((size_t)4096 * 512);
    ushort_t* fc_t   = alloc_us((size_t)128 * 512);

    // fp32 buffers
    float* o_x   = alloc_f((size_t)Me * 512);
    float* o_adj = alloc_f((size_t)B * 1089);

    // bf16 activation buffers
    ushort_t* o_xb  = alloc_us((size_t)Me * 512);
    ushort_t* o_xn  = alloc_us((size_t)Me * 512);
    ushort_t* o_q   = alloc_us((size_t)Me * 512);
    ushort_t* o_k   = alloc_us((size_t)Me * 512);
    ushort_t* o_vv  = alloc_us((size_t)Me * 512);
    ushort_t* o_v   = alloc_us((size_t)Mv * 512);
    ushort_t* o_rel = alloc_us((size_t)B * 1152);
    ushort_t* o_cls = alloc_us((size_t)Me * 128);

    float* out_adapted = (float*)d_out;
    float* out_cls     = out_adapted + (size_t)Me * 4096;

    // ---- weight conversion jobs
    WJobs J; int nb = 0, ji = 0;
    auto addjob = [&](const float* src, ushort_t* dst, int K, int N, int Kd) {
        J.j[ji].src = src; J.j[ji].dst = dst; J.j[ji].K = K; J.j[ji].N = N;
        J.j[ji].Kd = Kd; J.j[ji].block0 = nb;
        nb += ((Kd + 31) / 32) * ((N + 31) / 32);
        ++ji;
    };
    addjob(vis_W, vis_Wt, 2048, 512, 2048);
    addjob(ent_W, ent_Wt, 4096, 512, 4096);
    addjob(ca_Wq, caq_t, 512, 512, 512);
    addjob(ca_Wk, cak_t, 512, 512, 512);
    addjob(ca_Wv, cav_t, 512, 512, 512);
    addjob(ca_Wo, cao_t, 512, 512, 512);
    addjob(kp_W,  kp_t,  512, 512, 512);
    addjob(pred_W, pred_t, 1089, 1089, 1152);
    for (int i = 0; i < 3; ++i) {
        addjob(l_Wq   + (size_t)i * 262144, lw_t + (size_t)(i * 6 + 0) * 262144, 512, 512, 512);
        addjob(l_Wk   + (size_t)i * 262144, lw_t + (size_t)(i * 6 + 1) * 262144, 512, 512, 512);
        addjob(l_Wv   + (size_t)i * 262144, lw_t + (size_t)(i * 6 + 2) * 262144, 512, 512, 512);
        addjob(l_Wo   + (size_t)i * 262144, lw_t + (size_t)(i * 6 + 3) * 262144, 512, 512, 512);
        addjob(l_ffW1 + (size_t)i * 262144, lw_t + (size_t)(i * 6 + 4) * 262144, 512, 512, 512);
        addjob(l_ffW2 + (size_t)i * 262144, lw_t + (size_t)(i * 6 + 5) * 262144, 512, 512, 512);
    }
    addjob(ad_W1, ad1_t, 512, 512, 512);
    addjob(ad_W2, ad2_t, 512, 4096, 512);
    addjob(sc_fc_W, fc_t, 512, 128, 512);
    J.n = ji;

    dim3 blk(256);
    wcvt_k<<<dim3(nb), blk, 0, stream>>>(J);

    auto g2 = [](int M, int N) { return dim3((unsigned)((N + 127) / 128), (unsigned)(M / 128)); };
    dim3 attn_grid(8, B);

    // ---- input projections (fp32 A, converted in staging)
    mfma_gemm<0, true, true, false><<<g2(Mv, 512), blk, 0, stream>>>(
        visual, 2048, vis_Wt, 2048, vis_b, nullptr, nullptr, o_v, Mv, 512, 2048);
    mfma_gemm<0, true, true, false><<<g2(Me, 512), blk, 0, stream>>>(
        entity, 4096, ent_Wt, 4096, ent_b, nullptr, nullptr, o_xn, Me, 512, 4096);   // e -> o_xn

    // ---- cross attention
    mfma_gemm<0, false, true, false><<<g2(Me, 512), blk, 0, stream>>>(
        o_xn, 512, caq_t, 512, ca_bq, nullptr, nullptr, o_q, Me, 512, 512);
    mfma_gemm<0, false, true, false><<<g2(Mv, 512), blk, 0, stream>>>(
        o_v, 512, cak_t, 512, ca_bk, nullptr, nullptr, o_k, Mv, 512, 512);
    mfma_gemm<0, false, true, false><<<g2(Mv, 512), blk, 0, stream>>>(
        o_v, 512, cav_t, 512, ca_bv, nullptr, nullptr, o_vv, Mv, 512, 512);
    cross_attn_k<<<attn_grid, blk, 0, stream>>>(o_q, o_k, o_vv, o_xn);   // attc -> o_xn
    mfma_gemm<0, false, true, true><<<g2(Me, 512), blk, 0, stream>>>(
        o_xn, 512, cao_t, 512, ca_bo, nullptr, o_x, o_xb, Me, 512, 512); // ef -> x (f32+bf16)

    // ---- knowledge path
    mfma_gemm<0, false, true, false><<<g2(Me, 512), blk, 0, stream>>>(
        o_xb, 512, kp_t, 512, kp_b, nullptr, nullptr, o_q, Me, 512, 512);            // er
    rel_k<<<dim3(B), blk, 0, stream>>>(o_q, o_rel);
    mfma_gemm<4, false, false, true><<<g2(512, 1089), blk, 0, stream>>>(
        o_rel, 1152, pred_t, 1152, pred_b, graph, o_adj, nullptr, 512, 1089, 1152);  // adj

    // ---- 3 transformer layers
    for (int i = 0; i < 3; ++i) {
        const ushort_t* Wq = lw_t + (size_t)(i * 6 + 0) * 262144;
        const ushort_t* Wk = lw_t + (size_t)(i * 6 + 1) * 262144;
        const ushort_t* Wv = lw_t + (size_t)(i * 6 + 2) * 262144;
        const ushort_t* Wo = lw_t + (size_t)(i * 6 + 3) * 262144;
        const ushort_t* W1 = lw_t + (size_t)(i * 6 + 4) * 262144;
        const ushort_t* W2 = lw_t + (size_t)(i * 6 + 5) * 262144;

        ln_k<<<dim3(Me), blk, 0, stream>>>(o_x, l_n1_g + (size_t)i * 512, l_n1_b + (size_t)i * 512, o_xn);
        mfma_gemm<0, false, true, false><<<g2(Me, 512), blk, 0, stream>>>(
            o_xn, 512, Wq, 512, l_bq + (size_t)i * 512, nullptr, nullptr, o_q, Me, 512, 512);
        mfma_gemm<0, false, true, false><<<g2(Me, 512), blk, 0, stream>>>(
            o_xb, 512, Wk, 512, l_bk + (size_t)i * 512, nullptr, nullptr, o_k, Me, 512, 512);
        mfma_gemm<0, false, true, false><<<g2(Me, 512), blk, 0, stream>>>(
            o_xb, 512, Wv, 512, l_bv + (size_t)i * 512, nullptr, nullptr, o_vv, Me, 512, 512);
        self_attn_k<<<attn_grid, blk, 0, stream>>>(o_q, o_k, o_vv, o_adj, o_xn);
        mfma_gemm<2, false, true, true><<<g2(Me, 512), blk, 0, stream>>>(
            o_xn, 512, Wo, 512, l_bo + (size_t)i * 512, o_x, o_x, o_xb, Me, 512, 512);   // x += att
        ln_k<<<dim3(Me), blk, 0, stream>>>(o_x, l_n2_g + (size_t)i * 512, l_n2_b + (size_t)i * 512, o_xn);
        mfma_gemm<1, false, true, false><<<g2(Me, 512), blk, 0, stream>>>(
            o_xn, 512, W1, 512, l_ffb1 + (size_t)i * 512, nullptr, nullptr, o_q, Me, 512, 512); // relu
        mfma_gemm<2, false, true, true><<<g2(Me, 512), blk, 0, stream>>>(
            o_q, 512, W2, 512, l_ffb2 + (size_t)i * 512, o_x, o_x, o_xb, Me, 512, 512);  // x += ff
    }

    // ---- final LN + heads
    ln_k<<<dim3(Me), blk, 0, stream>>>(o_x, fin_g, fin_b, o_xn);   // emb
    mfma_gemm<0, false, true, false><<<g2(Me, 512), blk, 0, stream>>>(
        o_xn, 512, ad1_t, 512, ad_b1, nullptr, nullptr, o_q, Me, 512, 512);
    mfma_gemm<0, false, false, true><<<g2(Me, 4096), blk, 0, stream>>>(
        o_q, 512, ad2_t, 512, ad_b2, nullptr, out_adapted, nullptr, Me, 4096, 512);
    mfma_gemm<0, false, true, false><<<g2(Me, 128), blk, 0, stream>>>(
        o_xn, 512, fc_t, 512, sc_fc_b, nullptr, nullptr, o_cls, Me, 128, 512);
    cls_k<<<dim3(B), blk, 0, stream>>>(o_cls, sc_cls_W, sc_cls_b, out_cls);
}